// Round 8
// baseline (384.037 us; speedup 1.0000x reference)
//
#include <hip/hip_runtime.h>
#include <math.h>

#define B_ 64
#define T_ 577
#define E_ 768
#define H_ 64
#define N_ 576
#define GW_ 24

typedef float f32x4 __attribute__((ext_vector_type(4)));
typedef __bf16 bf16x8 __attribute__((ext_vector_type(8)));
typedef __bf16 bf16x4 __attribute__((ext_vector_type(4)));

__device__ __forceinline__ void split_bf16(float f, __bf16& h, __bf16& l) {
  h = (__bf16)f;
  l = (__bf16)(f - (float)h);
}

// ==================== Kernel 0: W -> split-bf16 fragment layout ====================
__global__ __launch_bounds__(256) void prep_w_kernel(
    const float* __restrict__ wq, const float* __restrict__ wk, const float* __restrict__ wv,
    __bf16* __restrict__ wsw_hi, __bf16* __restrict__ wsw_lo)
{
  int t = blockIdx.x * 256 + threadIdx.x;
  if (t >= 24*192) return;
  int kc = t / 192, n = t - (t/192)*192;
  const float* src = (n < 64) ? wq : ((n < 128) ? wk : wv);
  int nn = n & 63;
  __bf16 hbuf[32], lbuf[32];
  #pragma unroll
  for (int kk = 0; kk < 32; ++kk) {
    float f = src[(size_t)(kc*32 + kk)*64 + nn];
    split_bf16(f, hbuf[kk], lbuf[kk]);
  }
  size_t base = (size_t)t * 32;
  #pragma unroll
  for (int i = 0; i < 4; ++i) {
    *(bf16x8*)(wsw_hi + base + i*8) = *(bf16x8*)&hbuf[i*8];
    *(bf16x8*)(wsw_lo + base + i*8) = *(bf16x8*)&lbuf[i*8];
  }
}

// ==================== Kernel 1: MFMA qkv + LN + heads ====================
// 577 blocks x 64 rows, 4 waves, 3 blocks/CU. A staged in LDS (40-bf16 rows);
// B fragments straight from L2-resident wsw; depth-2 x prefetch.
__global__ __launch_bounds__(256, 3) void qkv_kernel(
    const float* __restrict__ x,
    const __bf16* __restrict__ wsw_hi, const __bf16* __restrict__ wsw_lo,
    const float* __restrict__ qg, const float* __restrict__ qb,
    const float* __restrict__ kg, const float* __restrict__ kb,
    const float* __restrict__ wsig, const float* __restrict__ bsig,
    const float* __restrict__ walp, const float* __restrict__ balp,
    float* __restrict__ qo, float* __restrict__ ko, float* __restrict__ vo,
    float* __restrict__ alo, float* __restrict__ sxo, float* __restrict__ syo)
{
  __shared__ __align__(16) float smem[64*193 + 256];   // 50432 B
  __bf16* A_hi = (__bf16*)smem;            // 64 x 40
  __bf16* A_lo = A_hi + 64*40;
  float (*Cs)[193] = (float (*)[193])smem;
  float* mu_q = smem + 64*193;
  float* rs_q = mu_q + 64;
  float* mu_k = rs_q + 64;
  float* rs_k = mu_k + 64;

  const int tid  = threadIdx.x;
  const int lane = tid & 63;
  const int w    = tid >> 6;
  const int rowbase = blockIdx.x << 6;

  f32x4 acc[4][3];
  #pragma unroll
  for (int mt = 0; mt < 4; ++mt)
    #pragma unroll
    for (int nt = 0; nt < 3; ++nt)
      acc[mt][nt] = (f32x4){0.f, 0.f, 0.f, 0.f};

  const int m     = lane & 15;
  const int kfrag = (lane >> 4) * 8;

  const int arow0 = tid >> 3,         ak0 = (tid & 7) * 4;   // rows 0..31
  const int arow1 = (tid + 256) >> 3, ak1 = (tid & 7) * 4;   // rows 32..63

  float4 xA0, xA1, xB0, xB1;   // two chunk-deep x prefetch (A=even slot, B=odd slot)

  auto loadA_A = [&](int kc) {
    int c = kc > 23 ? 23 : kc;
    xA0 = *(const float4*)(x + (size_t)(rowbase + arow0)*E_ + c*32 + ak0);
    xA1 = *(const float4*)(x + (size_t)(rowbase + arow1)*E_ + c*32 + ak1);
  };
  auto loadA_B = [&](int kc) {
    int c = kc > 23 ? 23 : kc;
    xB0 = *(const float4*)(x + (size_t)(rowbase + arow0)*E_ + c*32 + ak0);
    xB1 = *(const float4*)(x + (size_t)(rowbase + arow1)*E_ + c*32 + ak1);
  };
  auto storeA = [&](float4 r0, float4 r1) {
    __bf16 h0,l0,h1,l1,h2,l2,h3,l3;
    split_bf16(r0.x,h0,l0); split_bf16(r0.y,h1,l1);
    split_bf16(r0.z,h2,l2); split_bf16(r0.w,h3,l3);
    *(bf16x4*)&A_hi[arow0*40 + ak0] = (bf16x4){h0,h1,h2,h3};
    *(bf16x4*)&A_lo[arow0*40 + ak0] = (bf16x4){l0,l1,l2,l3};
    split_bf16(r1.x,h0,l0); split_bf16(r1.y,h1,l1);
    split_bf16(r1.z,h2,l2); split_bf16(r1.w,h3,l3);
    *(bf16x4*)&A_hi[arow1*40 + ak1] = (bf16x4){h0,h1,h2,h3};
    *(bf16x4*)&A_lo[arow1*40 + ak1] = (bf16x4){l0,l1,l2,l3};
  };
  auto loadB = [&](int kc, bf16x8* bh, bf16x8* bl) {
    int c = kc > 23 ? 23 : kc;
    #pragma unroll
    for (int nt = 0; nt < 3; ++nt) {
      size_t off = (size_t)c*6144 + (size_t)(w*48 + nt*16 + m)*32 + kfrag;
      bh[nt] = *(const bf16x8*)(wsw_hi + off);
      bl[nt] = *(const bf16x8*)(wsw_lo + off);
    }
  };
  auto mfma_step = [&](bf16x8* bh, bf16x8* bl) {
    #pragma unroll
    for (int mt = 0; mt < 4; ++mt) {
      bf16x8 ah = *(const bf16x8*)&A_hi[(mt*16 + m)*40 + kfrag];
      bf16x8 al = *(const bf16x8*)&A_lo[(mt*16 + m)*40 + kfrag];
      #pragma unroll
      for (int nt = 0; nt < 3; ++nt) {
        acc[mt][nt] = __builtin_amdgcn_mfma_f32_16x16x32_bf16(ah, bh[nt], acc[mt][nt], 0, 0, 0);
        acc[mt][nt] = __builtin_amdgcn_mfma_f32_16x16x32_bf16(al, bh[nt], acc[mt][nt], 0, 0, 0);
        acc[mt][nt] = __builtin_amdgcn_mfma_f32_16x16x32_bf16(ah, bl[nt], acc[mt][nt], 0, 0, 0);
      }
    }
  };

  bf16x8 bhC[3], blC[3], bhN[3], blN[3];
  loadA_A(0);        // chunk 0
  loadA_B(1);        // chunk 1
  loadB(0, bhC, blC);

  #pragma unroll 1
  for (int kc2 = 0; kc2 < 12; ++kc2) {
    int kc = kc2 * 2;
    // even chunk
    __syncthreads();
    storeA(xA0, xA1);
    __syncthreads();
    loadA_A(kc + 2);           // 2 chunks ahead
    loadB(kc + 1, bhN, blN);
    mfma_step(bhC, blC);
    // odd chunk
    __syncthreads();
    storeA(xB0, xB1);
    __syncthreads();
    loadA_B(kc + 3);
    loadB(kc + 2, bhC, blC);
    mfma_step(bhN, blN);
  }
  __syncthreads();   // stage dead; alias as C tile

  #pragma unroll
  for (int mt = 0; mt < 4; ++mt)
    #pragma unroll
    for (int nt = 0; nt < 3; ++nt) {
      int row = mt*16 + (lane >> 4)*4;
      int col = w*48 + nt*16 + (lane & 15);
      Cs[row + 0][col] = acc[mt][nt].x;
      Cs[row + 1][col] = acc[mt][nt].y;
      Cs[row + 2][col] = acc[mt][nt].z;
      Cs[row + 3][col] = acc[mt][nt].w;
    }
  __syncthreads();

  if (tid < 64) {
    float s = 0.f;
    for (int h = 0; h < 64; ++h) s += Cs[tid][h];
    float mu = s * (1.f/64.f);
    float vs = 0.f;
    for (int h = 0; h < 64; ++h) { float d = Cs[tid][h] - mu; vs += d*d; }
    mu_q[tid] = mu;
    rs_q[tid] = rsqrtf(vs*(1.f/64.f) + 1e-5f);
  } else if (tid < 128) {
    int r = tid - 64;
    float s = 0.f;
    for (int h = 0; h < 64; ++h) s += Cs[r][64+h];
    float mu = s * (1.f/64.f);
    float vs = 0.f;
    for (int h = 0; h < 64; ++h) { float d = Cs[r][64+h] - mu; vs += d*d; }
    mu_k[r] = mu;
    rs_k[r] = rsqrtf(vs*(1.f/64.f) + 1e-5f);
  }
  __syncthreads();

  if (tid >= 192) {
    int r = tid - 192;
    int mrow = rowbase + r;
    int tindex = mrow % T_;
    if (tindex >= 1) {
      int bb = mrow / T_;
      int g = tindex - 1;
      float mu = mu_q[r], rs = rs_q[r];
      float za = 0.f, z0 = 0.f, z1 = 0.f;
      for (int h = 0; h < 64; ++h) {
        float qv = (Cs[r][h] - mu) * rs * qg[h] + qb[h];
        za += qv * walp[h];
        z0 += qv * wsig[2*h];
        z1 += qv * wsig[2*h+1];
      }
      za += balp[0]; z0 += bsig[0]; z1 += bsig[1];
      float al = fmaxf(za, 0.f) + log1pf(__expf(-fabsf(za)));
      float sx = 1.f/(1.f + __expf(-z0));
      float sy = 1.f/(1.f + __expf(-z1));
      alo[bb*N_ + g] = al;
      sxo[bb*N_ + g] = 0.5f/(sx*sx);
      syo[bb*N_ + g] = 0.5f/(sy*sy);
    }
  }
  for (int idx = tid; idx < 64*48; idx += 256) {
    int r = idx / 48, c4 = (idx - (idx/48)*48) * 4;
    size_t row = (size_t)rowbase + r;
    float4 val = make_float4(Cs[r][c4], Cs[r][c4+1], Cs[r][c4+2], Cs[r][c4+3]);
    if (c4 < 64) {
      float mu = mu_q[r], rs = rs_q[r];
      float4 o;
      o.x = (val.x - mu)*rs*qg[c4+0] + qb[c4+0];
      o.y = (val.y - mu)*rs*qg[c4+1] + qb[c4+1];
      o.z = (val.z - mu)*rs*qg[c4+2] + qb[c4+2];
      o.w = (val.w - mu)*rs*qg[c4+3] + qb[c4+3];
      *(float4*)(qo + row*64 + c4) = o;
    } else if (c4 < 128) {
      int h = c4 - 64;
      float mu = mu_k[r], rs = rs_k[r];
      float4 o;
      o.x = (val.x - mu)*rs*kg[h+0] + kb[h+0];
      o.y = (val.y - mu)*rs*kg[h+1] + kb[h+1];
      o.z = (val.z - mu)*rs*kg[h+2] + kb[h+2];
      o.w = (val.w - mu)*rs*kg[h+3] + kb[h+3];
      *(float4*)(ko + row*64 + h) = o;
    } else {
      *(float4*)(vo + row*64 + (c4-128)) = val;
    }
  }
}

// ==================== Kernel 2: MFMA flash attention ====================
// grid 640: (b, 64-q-row tile); 4 waves; rows padded to 68 bf16; P aliased onto K.
// LDS = 6*8704 + 1536 = 53760 B -> 3 blocks/CU.
#define PAD_ 68
__global__ __launch_bounds__(256, 3) void attn_kernel(
    const float* __restrict__ q, const float* __restrict__ k, const float* __restrict__ v,
    const float* __restrict__ ala, const float* __restrict__ sxa, const float* __restrict__ sya,
    float* __restrict__ out)
{
  __shared__ __align__(16) char smraw[6*8704 + 1536];
  __bf16* sm = (__bf16*)smraw;
  __bf16* QH = sm;            __bf16* QL = sm + 4352;
  __bf16* KH = sm + 2*4352;   __bf16* KL = sm + 3*4352;   // K; reused as P after S
  __bf16* VH = sm + 4*4352;   __bf16* VL = sm + 5*4352;   // V^T: [dim][key]
  __bf16* PH = KH;            __bf16* PL = KL;
  float* prm_al = (float*)(smraw + 6*8704);
  float* prm_sx = prm_al + 64;
  float* prm_sy = prm_sx + 64;
  float* prm_gr = prm_sy + 64;
  float* prm_gc = prm_gr + 64;
  int*   prm_has = (int*)(prm_gc + 64);

  const int tid  = threadIdx.x;
  const int lane = tid & 63;
  const int w    = tid >> 6;
  const int quad = lane >> 4;
  const int mrow = lane & 15;
  const int b    = blockIdx.x / 10;
  const int qt   = blockIdx.x - b*10;

  const float* qbase = q + (size_t)b * T_ * H_;
  const float* kbase = k + (size_t)b * T_ * H_;
  const float* vbase = v + (size_t)b * T_ * H_;

  if (tid < 64) {
    int row = qt*64 + tid;
    float al=0.f, isx=0.f, isy=0.f, gr=0.f, gc=0.f; int has = 0;
    if (row >= 1 && row < T_) {
      int g = row - 1;
      al  = ala[b*N_ + g] * 0.125f;
      isx = sxa[b*N_ + g];
      isy = sya[b*N_ + g];
      gr  = (float)(g / GW_);
      gc  = (float)(g - (g/GW_)*GW_);
      has = 1;
    }
    prm_al[tid]=al; prm_sx[tid]=isx; prm_sy[tid]=isy;
    prm_gr[tid]=gr; prm_gc[tid]=gc; prm_has[tid]=has;
  }
  #pragma unroll
  for (int i = 0; i < 4; ++i) {
    int s = tid + 256*i;
    int r = s >> 4, c4 = (s & 15)*4;
    int row = qt*64 + r;
    int rowc = row < T_ ? row : T_ - 1;
    float4 v4 = *(const float4*)(qbase + (size_t)rowc*H_ + c4);
    v4.x *= 0.125f; v4.y *= 0.125f; v4.z *= 0.125f; v4.w *= 0.125f;
    __bf16 h0,l0,h1,l1,h2,l2,h3,l3;
    split_bf16(v4.x,h0,l0); split_bf16(v4.y,h1,l1);
    split_bf16(v4.z,h2,l2); split_bf16(v4.w,h3,l3);
    *(bf16x4*)&QH[r*PAD_ + c4] = (bf16x4){h0,h1,h2,h3};
    *(bf16x4*)&QL[r*PAD_ + c4] = (bf16x4){l0,l1,l2,l3};
  }
  __syncthreads();

  float p_al[4], p_sx[4], p_sy[4], p_gr[4], p_gc[4]; int p_has[4];
  #pragma unroll
  for (int reg = 0; reg < 4; ++reg) {
    int rr = w*16 + quad*4 + reg;
    p_al[reg]=prm_al[rr]; p_sx[reg]=prm_sx[rr]; p_sy[reg]=prm_sy[rr];
    p_gr[reg]=prm_gr[rr]; p_gc[reg]=prm_gc[rr]; p_has[reg]=prm_has[rr];
  }

  float mo[4], lsum[4], O_[4][4];
  #pragma unroll
  for (int reg = 0; reg < 4; ++reg) { mo[reg] = -INFINITY; lsum[reg] = 0.f; }
  #pragma unroll
  for (int nt = 0; nt < 4; ++nt)
    #pragma unroll
    for (int reg = 0; reg < 4; ++reg) O_[nt][reg] = 0.f;

  float4 kreg[4];
  float  vreg[16];
  const int d0 = tid & 15, k0 = (tid >> 4) * 4;

  auto load_kv = [&](int kt) {
    #pragma unroll
    for (int i = 0; i < 4; ++i) {
      int s = tid + 256*i;
      int key = s >> 4, c4 = (s & 15)*4;
      int kgl = kt*64 + key;
      int kcl = kgl < T_ ? kgl : T_ - 1;
      kreg[i] = *(const float4*)(kbase + (size_t)kcl*H_ + c4);
    }
    #pragma unroll
    for (int di = 0; di < 4; ++di)
      #pragma unroll
      for (int ki = 0; ki < 4; ++ki) {
        int kgl = kt*64 + k0 + ki;
        int kcl = kgl < T_ ? kgl : T_ - 1;
        vreg[di*4+ki] = vbase[(size_t)kcl*H_ + d0 + 16*di];
      }
  };
  auto store_kv = [&]() {
    #pragma unroll
    for (int i = 0; i < 4; ++i) {
      int s = tid + 256*i;
      int key = s >> 4, c4 = (s & 15)*4;
      __bf16 h0,l0,h1,l1,h2,l2,h3,l3;
      split_bf16(kreg[i].x,h0,l0); split_bf16(kreg[i].y,h1,l1);
      split_bf16(kreg[i].z,h2,l2); split_bf16(kreg[i].w,h3,l3);
      *(bf16x4*)&KH[key*PAD_ + c4] = (bf16x4){h0,h1,h2,h3};
      *(bf16x4*)&KL[key*PAD_ + c4] = (bf16x4){l0,l1,l2,l3};
    }
    #pragma unroll
    for (int di = 0; di < 4; ++di) {
      int dim = d0 + 16*di;
      __bf16 h0,l0,h1,l1,h2,l2,h3,l3;
      split_bf16(vreg[di*4+0],h0,l0); split_bf16(vreg[di*4+1],h1,l1);
      split_bf16(vreg[di*4+2],h2,l2); split_bf16(vreg[di*4+3],h3,l3);
      *(bf16x4*)&VH[dim*PAD_ + k0] = (bf16x4){h0,h1,h2,h3};
      *(bf16x4*)&VL[dim*PAD_ + k0] = (bf16x4){l0,l1,l2,l3};
    }
  };

  load_kv(0);
  #pragma unroll 1
  for (int kt = 0; kt < 10; ++kt) {
    __syncthreads();   // prior PV reads of P(K-region)/V done before overwrite
    store_kv();
    __syncthreads();
    if (kt < 9) load_kv(kt + 1);

    float S_[4][4];
    {
      f32x4 sac[4];
      #pragma unroll
      for (int nt = 0; nt < 4; ++nt) sac[nt] = (f32x4){0.f,0.f,0.f,0.f};
      #pragma unroll
      for (int ks = 0; ks < 2; ++ks) {
        int ko_ = ks*32 + quad*8;
        bf16x8 qh = *(const bf16x8*)&QH[(w*16 + mrow)*PAD_ + ko_];
        bf16x8 ql = *(const bf16x8*)&QL[(w*16 + mrow)*PAD_ + ko_];
        #pragma unroll
        for (int nt = 0; nt < 4; ++nt) {
          bf16x8 kh = *(const bf16x8*)&KH[(nt*16 + mrow)*PAD_ + ko_];
          bf16x8 kl = *(const bf16x8*)&KL[(nt*16 + mrow)*PAD_ + ko_];
          sac[nt] = __builtin_amdgcn_mfma_f32_16x16x32_bf16(qh, kh, sac[nt], 0, 0, 0);
          sac[nt] = __builtin_amdgcn_mfma_f32_16x16x32_bf16(ql, kh, sac[nt], 0, 0, 0);
          sac[nt] = __builtin_amdgcn_mfma_f32_16x16x32_bf16(qh, kl, sac[nt], 0, 0, 0);
        }
      }
      #pragma unroll
      for (int nt = 0; nt < 4; ++nt) {
        S_[nt][0] = sac[nt].x; S_[nt][1] = sac[nt].y;
        S_[nt][2] = sac[nt].z; S_[nt][3] = sac[nt].w;
      }
    }
    __syncthreads();   // all waves' K reads done before P overwrites the region

    #pragma unroll
    for (int nt = 0; nt < 4; ++nt) {
      int keyg = kt*64 + nt*16 + mrow;
      bool kval = keyg < T_;
      bool khas = (keyg >= 1) && kval;
      float kgf = (float)(keyg - 1);
      float krf = floorf(kgf * (1.0f/24.0f));
      float kcf = kgf - 24.f*krf;
      #pragma unroll
      for (int reg = 0; reg < 4; ++reg) {
        float sval = S_[nt][reg];
        float dx = p_gc[reg] - kcf, dy = p_gr[reg] - krf;
        float bias = p_al[reg] * __expf(-(dx*dx*p_sx[reg] + dy*dy*p_sy[reg]));
        sval += (khas && p_has[reg]) ? bias : 0.f;
        S_[nt][reg] = kval ? sval : -1e30f;
      }
    }

    float lt_[4], sc_[4], mn_[4];
    #pragma unroll
    for (int reg = 0; reg < 4; ++reg) {
      float mx = fmaxf(fmaxf(S_[0][reg], S_[1][reg]), fmaxf(S_[2][reg], S_[3][reg]));
      mx = fmaxf(mx, __shfl_xor(mx, 1, 64));
      mx = fmaxf(mx, __shfl_xor(mx, 2, 64));
      mx = fmaxf(mx, __shfl_xor(mx, 4, 64));
      mx = fmaxf(mx, __shfl_xor(mx, 8, 64));
      mn_[reg] = fmaxf(mo[reg], mx);
      lt_[reg] = 0.f;
    }
    #pragma unroll
    for (int nt = 0; nt < 4; ++nt)
      #pragma unroll
      for (int reg = 0; reg < 4; ++reg) {
        float p = __expf(S_[nt][reg] - mn_[reg]);
        S_[nt][reg] = p;
        lt_[reg] += p;
      }
    #pragma unroll
    for (int reg = 0; reg < 4; ++reg) {
      float ls = lt_[reg];
      ls += __shfl_xor(ls, 1, 64);
      ls += __shfl_xor(ls, 2, 64);
      ls += __shfl_xor(ls, 4, 64);
      ls += __shfl_xor(ls, 8, 64);
      sc_[reg] = __expf(mo[reg] - mn_[reg]);
      lsum[reg] = lsum[reg]*sc_[reg] + ls;
      mo[reg] = mn_[reg];
    }
    #pragma unroll
    for (int nt = 0; nt < 4; ++nt)
      #pragma unroll
      for (int reg = 0; reg < 4; ++reg) O_[nt][reg] *= sc_[reg];

    // pack P (hi/lo) into the K region: own 16-row band, same-wave RAW below
    #pragma unroll
    for (int nt = 0; nt < 4; ++nt)
      #pragma unroll
      for (int reg = 0; reg < 4; ++reg) {
        float p = S_[nt][reg];
        __bf16 ph, pl;
        split_bf16(p, ph, pl);
        int addr = (w*16 + quad*4 + reg)*PAD_ + nt*16 + mrow;
        PH[addr] = ph;
        PL[addr] = pl;
      }

    #pragma unroll
    for (int nt = 0; nt < 4; ++nt) {
      f32x4 c = (f32x4){O_[nt][0], O_[nt][1], O_[nt][2], O_[nt][3]};
      #pragma unroll
      for (int ks = 0; ks < 2; ++ks) {
        int ko_ = ks*32 + quad*8;
        bf16x8 pah  = *(const bf16x8*)&PH[(w*16 + mrow)*PAD_ + ko_];
        bf16x8 pall = *(const bf16x8*)&PL[(w*16 + mrow)*PAD_ + ko_];
        bf16x8 vh   = *(const bf16x8*)&VH[(nt*16 + mrow)*PAD_ + ko_];
        bf16x8 vl   = *(const bf16x8*)&VL[(nt*16 + mrow)*PAD_ + ko_];
        c = __builtin_amdgcn_mfma_f32_16x16x32_bf16(pah, vh, c, 0, 0, 0);
        c = __builtin_amdgcn_mfma_f32_16x16x32_bf16(pall, vh, c, 0, 0, 0);
        c = __builtin_amdgcn_mfma_f32_16x16x32_bf16(pah, vl, c, 0, 0, 0);
      }
      O_[nt][0] = c.x; O_[nt][1] = c.y; O_[nt][2] = c.z; O_[nt][3] = c.w;
    }
  }

  #pragma unroll
  for (int reg = 0; reg < 4; ++reg) {
    int rowg = qt*64 + w*16 + quad*4 + reg;
    if (rowg < T_) {
      float inv = 1.f / lsum[reg];
      #pragma unroll
      for (int nt = 0; nt < 4; ++nt) {
        out[((size_t)b*T_ + rowg)*H_ + nt*16 + mrow] = O_[nt][reg] * inv;
      }
    }
  }
}

extern "C" void kernel_launch(void* const* d_in, const int* in_sizes, int n_in,
                              void* d_out, int out_size, void* d_ws, size_t ws_size,
                              hipStream_t stream) {
  const float* x      = (const float*)d_in[0];
  const float* wq     = (const float*)d_in[1];
  const float* wk     = (const float*)d_in[2];
  const float* wv     = (const float*)d_in[3];
  const float* qg     = (const float*)d_in[4];
  const float* qb     = (const float*)d_in[5];
  const float* kg     = (const float*)d_in[6];
  const float* kb     = (const float*)d_in[7];
  const float* wsig   = (const float*)d_in[8];
  const float* bsig   = (const float*)d_in[9];
  const float* walp   = (const float*)d_in[10];
  const float* balp   = (const float*)d_in[11];
  float* out = (float*)d_out;

  float* ws  = (float*)d_ws;
  const size_t nrow = (size_t)B_ * T_;        // 36928
  float* qo  = ws;
  float* ko  = qo + nrow*H_;
  float* vo  = ko + nrow*H_;
  float* alo = vo + nrow*H_;
  float* sxo = alo + (size_t)B_*N_;
  float* syo = sxo + (size_t)B_*N_;
  __bf16* wsw_hi = (__bf16*)(syo + (size_t)B_*N_);
  __bf16* wsw_lo = wsw_hi + 24*192*32;

  hipLaunchKernelGGL(prep_w_kernel, dim3(18), dim3(256), 0, stream,
                     wq, wk, wv, wsw_hi, wsw_lo);
  hipLaunchKernelGGL(qkv_kernel, dim3(577), dim3(256), 0, stream,
                     x, wsw_hi, wsw_lo, qg, qb, kg, kb, wsig, bsig, walp, balp,
                     qo, ko, vo, alo, sxo, syo);
  hipLaunchKernelGGL(attn_kernel, dim3(640), dim3(256), 0, stream,
                     qo, ko, vo, alo, sxo, syo, out);
}